// Round 1
// baseline (32.654 us; speedup 1.0000x reference)
//
#include <hip/hip_runtime.h>

// B=4, N=512, D=64, Dm=64, Do=64 (fixed problem shape)
// Kernel A: A[r][m] = b_msg[m] + sum_d V[r][d]*W_msg[m][d]
//           C[r][m] = mask[r] ? sum_d V[r][d]*W_msg[m][64+d] : -1e30
// Kernel B: agg[r][m] = mask[r] ? sum_j relu(A[r][m] + C[(b,j)][m]) : 0
//           out[r][o] = relu(b_node[o] + sum_k V[r][k]*Wn[o][k] + sum_k agg[r][k]*Wn[o][64+k])

__global__ __launch_bounds__(256) void prep_ac(
    const float* __restrict__ V, const int* __restrict__ mask,
    const float* __restrict__ Wmsg, const float* __restrict__ bmsg,
    float* __restrict__ A, float* __restrict__ C, int BN)
{
    int gid  = blockIdx.x * 256 + threadIdx.x;
    int r    = gid >> 6;            // row (b*N + n)
    int m    = gid & 63;
    int rloc = threadIdx.x >> 6;    // 0..3
    __shared__ float v_s[4][64];
    if (r < BN) v_s[rloc][m] = V[r * 64 + m];
    __syncthreads();
    if (r >= BN) return;

    const float* wi = Wmsg + m * 128;   // row m of W_msg (128 wide: [Wi | Wj])
    float sa = bmsg[m];
    float sc = 0.f;
#pragma unroll
    for (int d = 0; d < 64; ++d) {
        float vd = v_s[rloc][d];        // broadcast across lanes (same addr)
        sa = fmaf(vd, wi[d], sa);
        sc = fmaf(vd, wi[64 + d], sc);
    }
    A[r * 64 + m] = sa;
    // bake j-mask into C: relu(a + (-1e30)) == 0 exactly
    C[r * 64 + m] = mask[r] ? sc : -1e30f;
}

#define IB 8     // rows per block
#define JT 128   // j-tile staged in LDS

__global__ __launch_bounds__(512) void agg_out(
    const float* __restrict__ V, const int* __restrict__ mask,
    const float* __restrict__ A, const float* __restrict__ C,
    const float* __restrict__ Wn, const float* __restrict__ bn,
    float* __restrict__ out, int N)
{
    int tid = threadIdx.x;
    int r   = tid >> 6;          // 0..7 local row
    int m   = tid & 63;          // channel
    int i0  = blockIdx.x * IB;   // global row base (8 rows, same batch since N%8==0)
    int row = i0 + r;
    int b   = i0 / N;
    const float* cb = C + (size_t)b * N * 64;

    __shared__ float c_s[JT][64];     // 32 KB
    __shared__ float agg_s[IB][64];   // 2 KB
    __shared__ float v_s[IB][64];     // 2 KB

    float a_reg = A[row * 64 + m];
    v_s[r][m] = V[row * 64 + m];

    float acc0 = 0.f, acc1 = 0.f, acc2 = 0.f, acc3 = 0.f;
    for (int j0 = 0; j0 < N; j0 += JT) {
        __syncthreads();
        // stage JT*64 = 8192 floats with 512 threads: 4 x float4 each, coalesced
        const float4* src = (const float4*)(cb + (size_t)j0 * 64);
        float4*       dst = (float4*)&c_s[0][0];
#pragma unroll
        for (int t = 0; t < 4; ++t) dst[tid + t * 512] = src[tid + t * 512];
        __syncthreads();
#pragma unroll
        for (int jj = 0; jj < JT; jj += 4) {
            acc0 += fmaxf(a_reg + c_s[jj + 0][m], 0.f);
            acc1 += fmaxf(a_reg + c_s[jj + 1][m], 0.f);
            acc2 += fmaxf(a_reg + c_s[jj + 2][m], 0.f);
            acc3 += fmaxf(a_reg + c_s[jj + 3][m], 0.f);
        }
    }
    float aggv = (acc0 + acc1) + (acc2 + acc3);
    aggv = mask[row] ? aggv : 0.f;
    agg_s[r][m] = aggv;
    __syncthreads();

    // fused node MLP: one output element per thread, o = m
    const float* w = Wn + m * 128;
    float s = bn[m];
#pragma unroll
    for (int k = 0; k < 64; ++k) s = fmaf(v_s[r][k], w[k], s);
#pragma unroll
    for (int k = 0; k < 64; ++k) s = fmaf(agg_s[r][k], w[64 + k], s);
    out[row * 64 + m] = fmaxf(s, 0.f);
}

extern "C" void kernel_launch(void* const* d_in, const int* in_sizes, int n_in,
                              void* d_out, int out_size, void* d_ws, size_t ws_size,
                              hipStream_t stream) {
    const float* V    = (const float*)d_in[0];
    const int*   mask = (const int*)d_in[1];
    const float* Wmsg = (const float*)d_in[2];
    const float* bmsg = (const float*)d_in[3];
    const float* Wn   = (const float*)d_in[4];
    const float* bn   = (const float*)d_in[5];
    float* outp = (float*)d_out;

    const int BN = in_sizes[1];   // B*N = 2048
    const int N  = 512;

    float* A = (float*)d_ws;
    float* C = A + (size_t)BN * 64;

    prep_ac<<<dim3((BN * 64 + 255) / 256), dim3(256), 0, stream>>>(V, mask, Wmsg, bmsg, A, C, BN);
    agg_out<<<dim3(BN / IB), dim3(512), 0, stream>>>(V, mask, A, C, Wn, bn, outp, N);
}

// Round 2
// 25.745 us; speedup vs baseline: 1.2684x; 1.2684x over previous
//
#include <hip/hip_runtime.h>

// B=4, N=512, D=64, Dm=64, Do=64 (fixed problem shape)
// prep_ac2: A[r][m] = b_msg[m] + sum_d V[r][d]*Wi[m][d]
//           C[r][m] = mask[r] ? sum_d V[r][d]*Wj[m][d] : -1e30  (bakes j-mask: relu(a-1e30)=0)
// agg_out2: agg[r][m] = mask[r] ? sum_j relu(A[r][m] + C[(b,j)][m]) : 0
//           out[r][o] = relu(b_node[o] + sum_k V[r][k]*Wn[o][k] + sum_k agg[r][k]*Wn[o][64+k])

#define PR 8   // rows per block, prep

__global__ __launch_bounds__(512) void prep_ac2(
    const float* __restrict__ V, const int* __restrict__ mask,
    const float* __restrict__ Wmsg, const float* __restrict__ bmsg,
    float* __restrict__ A, float* __restrict__ C)
{
    int tid = threadIdx.x;
    int i0  = blockIdx.x * PR;

    // Wmsg transposed in LDS, padded stride 65 to kill bank conflicts:
    // wT[dd][m] = Wmsg[m][dd], dd in [0,128), m in [0,64)
    __shared__ float wT[128 * 65];   // 33280 B
    __shared__ float v_s[PR][64];

    // stage Wmsg: coalesced global read; LDS write addr = dd*65+m,
    // consecutive i -> consecutive dd (m fixed) -> bank stride 65 -> conflict-free
#pragma unroll
    for (int k = 0; k < 16; ++k) {
        int i  = tid + k * 512;          // 0..8191
        int m  = i >> 7;
        int dd = i & 127;
        wT[dd * 65 + m] = Wmsg[i];
    }
    {
        int r = tid >> 6, m = tid & 63;
        v_s[r][m] = V[(i0 + r) * 64 + m];
    }
    __syncthreads();

    int r = tid >> 6;          // 0..7
    int m = tid & 63;
    int row = i0 + r;
    float sa = bmsg[m];
    float sc = 0.f;
#pragma unroll
    for (int d = 0; d < 64; ++d) {
        float vd = v_s[r][d];                    // broadcast (uniform addr)
        sa = fmaf(vd, wT[d * 65 + m], sa);       // lanes consecutive -> free
        sc = fmaf(vd, wT[(d + 64) * 65 + m], sc);
    }
    A[row * 64 + m] = sa;
    C[row * 64 + m] = mask[row] ? sc : -1e30f;
}

#define IB 8     // rows per block
#define JT 256   // j-tile staged in LDS per outer iteration

__global__ __launch_bounds__(1024) void agg_out2(
    const float* __restrict__ V, const int* __restrict__ mask,
    const float* __restrict__ A, const float* __restrict__ C,
    const float* __restrict__ Wn, const float* __restrict__ bn,
    float* __restrict__ out, int N)
{
    int tid = threadIdx.x;
    int jh  = tid >> 9;          // 0/1: which half of each j-tile
    int rm  = tid & 511;
    int r   = rm >> 6;           // 0..7 local row
    int m   = rm & 63;           // channel
    int i0  = blockIdx.x * IB;
    int row = i0 + r;
    int b   = i0 / N;
    const float* cb = C + (size_t)b * N * 64;

    __shared__ float c_s[JT][64];      // 64 KB
    __shared__ float v_s[IB][64];
    __shared__ float agg_s[IB][64];
    __shared__ float part_s[2][IB][64];

    float a_reg = A[row * 64 + m];
    if (jh == 0) v_s[r][m] = V[row * 64 + m];

    float acc0 = 0.f, acc1 = 0.f, acc2 = 0.f, acc3 = 0.f;
    for (int j0 = 0; j0 < N; j0 += JT) {
        __syncthreads();
        // stage JT*64 = 16384 floats with 1024 threads: 4 x float4 each, coalesced
        const float4* src = (const float4*)(cb + (size_t)j0 * 64);
        float4*       dst = (float4*)&c_s[0][0];
#pragma unroll
        for (int t = 0; t < 4; ++t) dst[tid + t * 1024] = src[tid + t * 1024];
        __syncthreads();
        const float* cc = &c_s[jh * 128][0];
#pragma unroll
        for (int jj = 0; jj < 128; jj += 4) {
            acc0 += fmaxf(a_reg + cc[(jj + 0) * 64 + m], 0.f);
            acc1 += fmaxf(a_reg + cc[(jj + 1) * 64 + m], 0.f);
            acc2 += fmaxf(a_reg + cc[(jj + 2) * 64 + m], 0.f);
            acc3 += fmaxf(a_reg + cc[(jj + 3) * 64 + m], 0.f);
        }
    }
    part_s[jh][r][m] = (acc0 + acc1) + (acc2 + acc3);
    __syncthreads();

    if (tid < 512) {
        float aggv = part_s[0][r][m] + part_s[1][r][m];
        agg_s[r][m] = mask[row] ? aggv : 0.f;
    }
    __syncthreads();

    if (tid < 512) {
        // fused node MLP: one output element per thread, o = m
        const float* w = Wn + m * 128;
        float s = bn[m];
#pragma unroll
        for (int k = 0; k < 64; ++k) s = fmaf(v_s[r][k], w[k], s);
#pragma unroll
        for (int k = 0; k < 64; ++k) s = fmaf(agg_s[r][k], w[64 + k], s);
        out[row * 64 + m] = fmaxf(s, 0.f);
    }
}

extern "C" void kernel_launch(void* const* d_in, const int* in_sizes, int n_in,
                              void* d_out, int out_size, void* d_ws, size_t ws_size,
                              hipStream_t stream) {
    const float* V    = (const float*)d_in[0];
    const int*   mask = (const int*)d_in[1];
    const float* Wmsg = (const float*)d_in[2];
    const float* bmsg = (const float*)d_in[3];
    const float* Wn   = (const float*)d_in[4];
    const float* bn   = (const float*)d_in[5];
    float* outp = (float*)d_out;

    const int BN = in_sizes[1];   // B*N = 2048
    const int N  = 512;

    float* A = (float*)d_ws;
    float* Cc = A + (size_t)BN * 64;

    prep_ac2<<<dim3(BN / PR), dim3(512), 0, stream>>>(V, mask, Wmsg, bmsg, A, Cc);
    agg_out2<<<dim3(BN / IB), dim3(1024), 0, stream>>>(V, mask, A, Cc, Wn, bn, outp, N);
}

// Round 3
// 20.704 us; speedup vs baseline: 1.5772x; 1.2435x over previous
//
#include <hip/hip_runtime.h>

// B=4, N=512, D=64, Dm=64, Do=64.
// prep3:  A[r][m]  = b_msg[m] + sum_d V[r][d]*Wi[m][d]
//         C[r][m]  = mask[r] ? sum_d V[r][d]*Wj[m][d] : -1e30   (bakes j-mask)
//         O1[r][o] = b_node[o] + sum_d V[r][d]*Wn[o][d]         (V-half of node GEMM)
// agg3:   agg[r][m] = mask[r] ? sum_j relu(A[r][m] + C[b][j][m]) : 0
//         out[r][o] = relu(O1[r][o] + sum_k agg[r][k]*Wn[o][64+k])

typedef float v2f __attribute__((ext_vector_type(2)));

__device__ __forceinline__ v2f pk_add(v2f a, v2f b) {
    v2f d;
    asm("v_pk_add_f32 %0, %1, %2" : "=v"(d) : "v"(a), "v"(b));
    return d;
}

// ---------------- prep3: grid 256 x 256thr, 8 rows/block, 2 rows/thread ----
__global__ __launch_bounds__(256) void prep3(
    const float* __restrict__ V, const int* __restrict__ mask,
    const float* __restrict__ Wmsg, const float* __restrict__ bmsg,
    const float* __restrict__ Wn, const float* __restrict__ bn,
    float* __restrict__ A, float* __restrict__ C, float* __restrict__ O1)
{
    __shared__ float wm_s[64 * 132];   // Wmsg[m][dd], dd 0..127, stride 132 (pad, 16B-aligned)
    __shared__ float wn1_s[64 * 68];   // Wn[o][k], k 0..63, stride 68
    int tid = threadIdx.x;

    // stage Wmsg: 2048 float4, 8 per thread, coalesced
#pragma unroll
    for (int k = 0; k < 8; ++k) {
        int f4 = tid + k * 256;
        int mm = f4 >> 5, dd = (f4 & 31) << 2;
        *(float4*)&wm_s[mm * 132 + dd] = ((const float4*)Wmsg)[f4];
    }
    // stage Wn[:, 0:64]: 1024 float4, 4 per thread
#pragma unroll
    for (int k = 0; k < 4; ++k) {
        int f4 = tid + k * 256;
        int oo = f4 >> 4, kk = (f4 & 15) << 2;
        *(float4*)&wn1_s[oo * 68 + kk] = *(const float4*)&Wn[oo * 128 + kk];
    }
    __syncthreads();

    int m  = tid & 63;
    int rq = tid >> 6;                         // wave id, uniform per wave
    int row0 = __builtin_amdgcn_readfirstlane(blockIdx.x * 8 + rq * 2);
    const float* v0 = V + row0 * 64;           // wave-uniform -> scalar loads
    const float* v1 = v0 + 64;

    float sa0 = bmsg[m], sa1 = sa0;
    float sc0 = 0.f, sc1 = 0.f;
    float so0 = bn[m], so1 = so0;
#pragma unroll
    for (int d0 = 0; d0 < 64; d0 += 4) {
        float4 wa = *(float4*)&wm_s[m * 132 + d0];
        float4 wc = *(float4*)&wm_s[m * 132 + 64 + d0];
        float4 wo = *(float4*)&wn1_s[m * 68 + d0];
        float4 va = *(const float4*)&v0[d0];
        float4 vb = *(const float4*)&v1[d0];
        sa0 = fmaf(va.x, wa.x, sa0); sa0 = fmaf(va.y, wa.y, sa0);
        sa0 = fmaf(va.z, wa.z, sa0); sa0 = fmaf(va.w, wa.w, sa0);
        sc0 = fmaf(va.x, wc.x, sc0); sc0 = fmaf(va.y, wc.y, sc0);
        sc0 = fmaf(va.z, wc.z, sc0); sc0 = fmaf(va.w, wc.w, sc0);
        so0 = fmaf(va.x, wo.x, so0); so0 = fmaf(va.y, wo.y, so0);
        so0 = fmaf(va.z, wo.z, so0); so0 = fmaf(va.w, wo.w, so0);
        sa1 = fmaf(vb.x, wa.x, sa1); sa1 = fmaf(vb.y, wa.y, sa1);
        sa1 = fmaf(vb.z, wa.z, sa1); sa1 = fmaf(vb.w, wa.w, sa1);
        sc1 = fmaf(vb.x, wc.x, sc1); sc1 = fmaf(vb.y, wc.y, sc1);
        sc1 = fmaf(vb.z, wc.z, sc1); sc1 = fmaf(vb.w, wc.w, sc1);
        so1 = fmaf(vb.x, wo.x, so1); so1 = fmaf(vb.y, wo.y, so1);
        so1 = fmaf(vb.z, wo.z, so1); so1 = fmaf(vb.w, wo.w, so1);
    }
    int mk0 = mask[row0], mk1 = mask[row0 + 1];
    A [row0 * 64 + m]       = sa0;
    A [(row0 + 1) * 64 + m] = sa1;
    C [row0 * 64 + m]       = mk0 ? sc0 : -1e30f;
    C [(row0 + 1) * 64 + m] = mk1 ? sc1 : -1e30f;
    O1[row0 * 64 + m]       = so0;
    O1[(row0 + 1) * 64 + m] = so1;
}

// ---------------- agg3: grid 256 x 1024thr, 8 rows/block ------------------
__global__ __launch_bounds__(1024) void agg3(
    const int* __restrict__ mask,
    const float* __restrict__ A, const float* __restrict__ C,
    const float* __restrict__ O1, const float* __restrict__ Wn,
    float* __restrict__ out)
{
    __shared__ float smem[8192];       // c-tile [128][64], later part[16][8][64]
    __shared__ float wn2_s[64 * 68];   // Wn[o][64+k], stride 68
    __shared__ float agg_s[8 * 64];

    int tid = threadIdx.x;
    int m  = tid & 63;
    int jc = tid >> 6;                 // 0..15 j-chunk
    int i0 = blockIdx.x * 8;
    int b  = blockIdx.x >> 6;          // 64 blocks per batch
    const float* cb = C + (size_t)b * 512 * 64;

    // stage Wn[:, 64:128]: 1024 float4, 1 per thread
    {
        int oo = tid >> 4, kk = (tid & 15) << 2;
        *(float4*)&wn2_s[oo * 68 + kk] = *(const float4*)&Wn[oo * 128 + 64 + kk];
    }

    v2f ad[8], acc[8];
#pragma unroll
    for (int r = 0; r < 8; ++r) {
        float a = A[(i0 + r) * 64 + m];
        ad[r]  = (v2f){a, a};
        acc[r] = (v2f){0.f, 0.f};
    }

    for (int j0 = 0; j0 < 512; j0 += 128) {
        __syncthreads();               // previous tile fully consumed
        const float4* src = (const float4*)(cb + (size_t)j0 * 64);
        float4* dst = (float4*)smem;
        dst[tid]        = src[tid];
        dst[tid + 1024] = src[tid + 1024];
        __syncthreads();
        const float* cbase = smem + jc * 8 * 64 + m;   // my 8 j's of this tile
#pragma unroll
        for (int p = 0; p < 4; ++p) {
            v2f c2 = {cbase[p * 128], cbase[p * 128 + 64]};   // j pair (2p, 2p+1)
#pragma unroll
            for (int r = 0; r < 8; ++r) {
                v2f x = pk_add(ad[r], c2);
                x.x = fmaxf(x.x, 0.f);
                x.y = fmaxf(x.y, 0.f);
                acc[r] = pk_add(acc[r], x);
            }
        }
    }
    __syncthreads();                   // done reading c-tile; repurpose smem
#pragma unroll
    for (int r = 0; r < 8; ++r)
        smem[jc * 512 + r * 64 + m] = acc[r].x + acc[r].y;   // part[jc][r][m]
    __syncthreads();

    if (tid < 512) {
        int r = tid >> 6;
        float aggsum = 0.f;
#pragma unroll
        for (int q = 0; q < 16; ++q) aggsum += smem[q * 512 + r * 64 + m];
        agg_s[r * 64 + m] = mask[i0 + r] ? aggsum : 0.f;
    }
    __syncthreads();
    if (tid < 512) {
        int r = tid >> 6;
        float s = O1[(i0 + r) * 64 + m];
#pragma unroll
        for (int k = 0; k < 64; k += 4) {
            float4 h4 = *(float4*)&agg_s[r * 64 + k];          // wave-uniform bcast
            float4 w4 = *(float4*)&wn2_s[m * 68 + k];
            s = fmaf(h4.x, w4.x, s); s = fmaf(h4.y, w4.y, s);
            s = fmaf(h4.z, w4.z, s); s = fmaf(h4.w, w4.w, s);
        }
        out[(i0 + r) * 64 + m] = fmaxf(s, 0.f);
    }
}

extern "C" void kernel_launch(void* const* d_in, const int* in_sizes, int n_in,
                              void* d_out, int out_size, void* d_ws, size_t ws_size,
                              hipStream_t stream) {
    const float* V    = (const float*)d_in[0];
    const int*   mask = (const int*)d_in[1];
    const float* Wmsg = (const float*)d_in[2];
    const float* bmsg = (const float*)d_in[3];
    const float* Wn   = (const float*)d_in[4];
    const float* bn   = (const float*)d_in[5];
    float* outp = (float*)d_out;

    const int BN = in_sizes[1];        // 2048
    float* A  = (float*)d_ws;
    float* Cc = A  + (size_t)BN * 64;
    float* O1 = Cc + (size_t)BN * 64;

    prep3<<<dim3(BN / 8), dim3(256),  0, stream>>>(V, mask, Wmsg, bmsg, Wn, bn, A, Cc, O1);
    agg3 <<<dim3(BN / 8), dim3(1024), 0, stream>>>(mask, A, Cc, O1, Wn, outp);
}